// Round 1
// baseline (9029.613 us; speedup 1.0000x reference)
//
#include <hip/hip_runtime.h>
#include <math.h>

#define Bb 64
#define Ss 512
#define Hh 256
#define Vv 32000
#define BS (Bb*Ss)      // 32768
#define NSTEPS 10

// ---------------------------------------------------------------------------
// h0 = emb[x]  : gather rows, float4-vectorized
// ---------------------------------------------------------------------------
__global__ __launch_bounds__(256)
void k_embed(const int* __restrict__ x, const float* __restrict__ emb,
             float* __restrict__ h) {
    int idx = blockIdx.x * 256 + threadIdx.x;       // float4 index
    if (idx >= BS * Hh / 4) return;
    int row = idx >> 6;                             // / (H/4)
    int c4  = idx & 63;
    long long tok = x[row];
    reinterpret_cast<float4*>(h)[idx] =
        reinterpret_cast<const float4*>(emb)[tok * 64 + c4];
}

// ---------------------------------------------------------------------------
// m[b,s,:] = h[b,s-1]@W0 + h[b,s+1]@W1 + h[b,s]@W2  (+ boundary-aware biases)
// One GEMM, K=768 (3 segments of 256, A-rows shifted per segment).
// Tile 64 rows x 64 cols, 256 threads, 4x4 microtile.
// ---------------------------------------------------------------------------
__global__ __launch_bounds__(256)
void k_edges(const float* __restrict__ h, const float* __restrict__ W_edge,
             const float* __restrict__ b_edge, float* __restrict__ m) {
    __shared__ float As[64][33];
    __shared__ float Bs[32][64];
    const int t      = threadIdx.x;
    const int rowBlk = blockIdx.y * 64;
    const int colBlk = blockIdx.x * 64;
    const int ty = t >> 4, tx = t & 15;
    float acc[4][4] = {};

    for (int kc = 0; kc < 24; ++kc) {
        const int k0  = kc * 32;
        const int seg = k0 >> 8;          // 0: fwd(s-1), 1: bwd(s+1), 2: self
        const int kk0 = k0 & 255;
        // --- A tile: 64 rows x 32 k  (512 float4, 2 per thread), shifted rows
        #pragma unroll
        for (int i = 0; i < 2; ++i) {
            int lin = t + i * 256;
            int r   = lin >> 3;
            int kq  = lin & 7;
            int grow = rowBlk + r;
            int s    = grow & (Ss - 1);
            int srcs = (seg == 0) ? s - 1 : (seg == 1) ? s + 1 : s;
            float4 v = make_float4(0.f, 0.f, 0.f, 0.f);
            if (srcs >= 0 && srcs < Ss) {
                int srow = (grow & ~(Ss - 1)) + srcs;   // same batch b
                v = reinterpret_cast<const float4*>(h)[srow * 64 + (kk0 >> 2) + kq];
            }
            As[r][kq*4+0] = v.x; As[r][kq*4+1] = v.y;
            As[r][kq*4+2] = v.z; As[r][kq*4+3] = v.w;
        }
        // --- B tile: 32 k x 64 n from W_edge[seg]
        const float* Wseg = W_edge + seg * Hh * Hh;
        #pragma unroll
        for (int i = 0; i < 2; ++i) {
            int lin = t + i * 256;
            int kr  = lin >> 4;
            int nq  = lin & 15;
            float4 v = reinterpret_cast<const float4*>(Wseg + (kk0 + kr) * Hh + colBlk)[nq];
            *reinterpret_cast<float4*>(&Bs[kr][nq * 4]) = v;
        }
        __syncthreads();
        #pragma unroll
        for (int kk = 0; kk < 32; ++kk) {
            float a[4], b[4];
            #pragma unroll
            for (int i = 0; i < 4; ++i) a[i] = As[ty*4+i][kk];
            #pragma unroll
            for (int j = 0; j < 4; ++j) b[j] = Bs[kk][tx*4+j];
            #pragma unroll
            for (int i = 0; i < 4; ++i)
                #pragma unroll
                for (int j = 0; j < 4; ++j)
                    acc[i][j] += a[i] * b[j];
        }
        __syncthreads();
    }
    // --- epilogue: boundary-aware bias (pad drops b_edge[0] at s=0, b_edge[1] at s=S-1)
    #pragma unroll
    for (int i = 0; i < 4; ++i) {
        int grow = rowBlk + ty*4 + i;
        int s    = grow & (Ss - 1);
        #pragma unroll
        for (int j = 0; j < 4; ++j) {
            int n = colBlk + tx*4 + j;
            float bias = b_edge[2*Hh + n]
                       + (s > 0      ? b_edge[0*Hh + n] : 0.f)
                       + (s < Ss - 1 ? b_edge[1*Hh + n] : 0.f);
            m[grow * Hh + n] = acc[i][j] + bias;
        }
    }
}

// ---------------------------------------------------------------------------
// Fused GRU step: gi = m@W_ih.T, gh = h@W_hh.T, pointwise GRU -> hout.
// Tile 64 rows x 32 H-cols; 6 accumulators (i_r,i_z,i_n,h_r,h_z,h_n) per elem.
// ---------------------------------------------------------------------------
__global__ __launch_bounds__(256)
void k_gru(const float* __restrict__ m, const float* __restrict__ hin,
           float* __restrict__ hout,
           const float* __restrict__ W_ih, const float* __restrict__ W_hh,
           const float* __restrict__ b_ih, const float* __restrict__ b_hh) {
    __shared__ float Ms[64][33];
    __shared__ float Hs[64][33];
    __shared__ float Wi[3][32][33];
    __shared__ float Wh[3][32][33];
    const int t      = threadIdx.x;
    const int rowBlk = blockIdx.y * 64;
    const int n0     = blockIdx.x * 32;
    const int ty = t >> 4, tx = t & 15;
    float air[4][2] = {}, aiz[4][2] = {}, ain[4][2] = {};
    float ahr[4][2] = {}, ahz[4][2] = {}, ahn[4][2] = {};

    for (int kc = 0; kc < 8; ++kc) {
        const int k0 = kc * 32;
        // --- A tiles (m rows and h rows), 2 float4 each per thread
        #pragma unroll
        for (int i = 0; i < 2; ++i) {
            int lin = t + i * 256;
            int r   = lin >> 3;
            int kq  = lin & 7;
            float4 vm = reinterpret_cast<const float4*>(m  )[(rowBlk + r) * 64 + (k0 >> 2) + kq];
            float4 vh = reinterpret_cast<const float4*>(hin)[(rowBlk + r) * 64 + (k0 >> 2) + kq];
            Ms[r][kq*4+0] = vm.x; Ms[r][kq*4+1] = vm.y; Ms[r][kq*4+2] = vm.z; Ms[r][kq*4+3] = vm.w;
            Hs[r][kq*4+0] = vh.x; Hs[r][kq*4+1] = vh.y; Hs[r][kq*4+2] = vh.z; Hs[r][kq*4+3] = vh.w;
        }
        // --- weight tiles: W[g] rows (n0..n0+31) x k chunk, stored [kk][nn]
        {
            int nn = t >> 3, kq = t & 7;
            #pragma unroll
            for (int g = 0; g < 3; ++g) {
                float4 wi = reinterpret_cast<const float4*>(W_ih)[((g*Hh + n0 + nn) * Hh + k0) / 4 + kq];
                float4 wh = reinterpret_cast<const float4*>(W_hh)[((g*Hh + n0 + nn) * Hh + k0) / 4 + kq];
                Wi[g][kq*4+0][nn] = wi.x; Wi[g][kq*4+1][nn] = wi.y;
                Wi[g][kq*4+2][nn] = wi.z; Wi[g][kq*4+3][nn] = wi.w;
                Wh[g][kq*4+0][nn] = wh.x; Wh[g][kq*4+1][nn] = wh.y;
                Wh[g][kq*4+2][nn] = wh.z; Wh[g][kq*4+3][nn] = wh.w;
            }
        }
        __syncthreads();
        #pragma unroll
        for (int kk = 0; kk < 32; ++kk) {
            float mv[4], hv[4];
            #pragma unroll
            for (int i = 0; i < 4; ++i) { mv[i] = Ms[ty*4+i][kk]; hv[i] = Hs[ty*4+i][kk]; }
            #pragma unroll
            for (int j = 0; j < 2; ++j) {
                int n = tx*2 + j;
                float wir = Wi[0][kk][n], wiz = Wi[1][kk][n], win = Wi[2][kk][n];
                float whr = Wh[0][kk][n], whz = Wh[1][kk][n], whn = Wh[2][kk][n];
                #pragma unroll
                for (int i = 0; i < 4; ++i) {
                    air[i][j] += mv[i] * wir;  aiz[i][j] += mv[i] * wiz;  ain[i][j] += mv[i] * win;
                    ahr[i][j] += hv[i] * whr;  ahz[i][j] += hv[i] * whz;  ahn[i][j] += hv[i] * whn;
                }
            }
        }
        __syncthreads();
    }
    // --- GRU pointwise epilogue
    #pragma unroll
    for (int i = 0; i < 4; ++i) {
        int row = rowBlk + ty*4 + i;
        #pragma unroll
        for (int j = 0; j < 2; ++j) {
            int n = n0 + tx*2 + j;
            float ir  = air[i][j] + b_ih[n];
            float iz  = aiz[i][j] + b_ih[Hh + n];
            float in_ = ain[i][j] + b_ih[2*Hh + n];
            float hr  = ahr[i][j] + b_hh[n];
            float hz  = ahz[i][j] + b_hh[Hh + n];
            float hn  = ahn[i][j] + b_hh[2*Hh + n];
            float r  = 1.f / (1.f + expf(-(ir + hr)));
            float z  = 1.f / (1.f + expf(-(iz + hz)));
            float ng = tanhf(in_ + r * hn);
            float hold = hin[row * Hh + n];
            hout[row * Hh + n] = (1.f - z) * ng + z * hold;
        }
    }
}

// ---------------------------------------------------------------------------
// out = last @ out_w.T + out_b ; last = h[:, S-1, :]  (64 x 256) @ (256 x 32000)
// Stage `last` in LDS; each thread owns one vocab column, 64 row-accumulators.
// ---------------------------------------------------------------------------
__global__ __launch_bounds__(256)
void k_out(const float* __restrict__ h, const float* __restrict__ out_w,
           const float* __restrict__ out_b, float* __restrict__ out) {
    __shared__ float L[Bb][Hh + 1];
    const int t = threadIdx.x;
    #pragma unroll
    for (int i = 0; i < 16; ++i) {
        int lin = t + i * 256;          // float4 index into 64x256
        int r = lin >> 6, c4 = lin & 63;
        float4 v = reinterpret_cast<const float4*>(h)[(r * Ss + (Ss - 1)) * 64 + c4];
        L[r][c4*4+0] = v.x; L[r][c4*4+1] = v.y; L[r][c4*4+2] = v.z; L[r][c4*4+3] = v.w;
    }
    __syncthreads();
    const int n = blockIdx.x * 256 + t;           // V = 125 * 256 exactly
    float acc[Bb];
    #pragma unroll
    for (int r = 0; r < Bb; ++r) acc[r] = 0.f;
    const float4* wr = reinterpret_cast<const float4*>(out_w) + n * 64;
    for (int k4 = 0; k4 < 64; ++k4) {
        float4 w = wr[k4];
        #pragma unroll
        for (int r = 0; r < Bb; ++r) {
            acc[r] += L[r][k4*4+0]*w.x + L[r][k4*4+1]*w.y
                    + L[r][k4*4+2]*w.z + L[r][k4*4+3]*w.w;
        }
    }
    float bb = out_b[n];
    #pragma unroll
    for (int r = 0; r < Bb; ++r) out[r * Vv + n] = acc[r] + bb;
}

// ---------------------------------------------------------------------------
extern "C" void kernel_launch(void* const* d_in, const int* in_sizes, int n_in,
                              void* d_out, int out_size, void* d_ws, size_t ws_size,
                              hipStream_t stream) {
    const int*   x      = (const int*)  d_in[0];
    const float* emb    = (const float*)d_in[1];
    const float* W_edge = (const float*)d_in[2];
    const float* b_edge = (const float*)d_in[3];
    const float* W_ih   = (const float*)d_in[4];
    const float* W_hh   = (const float*)d_in[5];
    const float* b_ih   = (const float*)d_in[6];
    const float* b_hh   = (const float*)d_in[7];
    const float* out_w  = (const float*)d_in[8];
    const float* out_b  = (const float*)d_in[9];
    float* out = (float*)d_out;

    // workspace: hA | hB | m   (3 x 32768 x 256 floats = 100.7 MB)
    float* hA = (float*)d_ws;
    float* hB = hA + (size_t)BS * Hh;
    float* mm = hB + (size_t)BS * Hh;

    k_embed<<<BS * Hh / 4 / 256, 256, 0, stream>>>(x, emb, hA);

    float* cur = hA;
    float* nxt = hB;
    for (int step = 0; step < NSTEPS; ++step) {
        k_edges<<<dim3(Hh/64, BS/64), 256, 0, stream>>>(cur, W_edge, b_edge, mm);
        k_gru  <<<dim3(Hh/32, BS/64), 256, 0, stream>>>(mm, cur, nxt, W_ih, W_hh, b_ih, b_hh);
        float* tmp = cur; cur = nxt; nxt = tmp;
    }
    k_out<<<Vv / 256, 256, 0, stream>>>(cur, out_w, out_b, out);
}

// Round 2
// 1127.417 us; speedup vs baseline: 8.0091x; 8.0091x over previous
//
#include <hip/hip_runtime.h>
#include <math.h>

#define Bb 64
#define Ss 512
#define Hh 256
#define Vv 32000
#define BS (Bb*Ss)      // 32768
#define NSTEPS 10

typedef __attribute__((ext_vector_type(8))) short bf16x8;   // 8 bf16 = 4 VGPR
typedef __attribute__((ext_vector_type(4))) float f32x4;    // MFMA C/D frag
typedef unsigned short u16;

#define MFMA(a,b,c) __builtin_amdgcn_mfma_f32_16x16x32_bf16((a),(b),(c),0,0,0)

__device__ __forceinline__ u16 f2bf(float f) {              // RNE
    unsigned u = __float_as_uint(f);
    u += 0x7fffu + ((u >> 16) & 1u);
    return (u16)(u >> 16);
}
__device__ __forceinline__ float bf2f(u16 h) {
    return __uint_as_float(((unsigned)h) << 16);
}
// LDS chunk index for 16B chunk (row, kc) of a [rows][32]-bf16 tile,
// XOR-swizzled so MFMA fragment ds_read_b128 is 2-way (free) on banks.
__device__ __forceinline__ int swz(int r, int kc) { return ((r << 2) + kc) ^ (r & 7); }

// ---------------------------------------------------------------------------
// prep: W_edge [3][K=256][N=256] -> WeT bf16 [3][N][K] (B^T layout)
// ---------------------------------------------------------------------------
__global__ __launch_bounds__(256)
void k_prep_wet(const float* __restrict__ W, u16* __restrict__ WeT) {
    int id = blockIdx.x * 256 + threadIdx.x;        // 3*65536
    int g = id >> 16, n = (id >> 8) & 255, k = id & 255;
    WeT[id] = f2bf(W[(g << 16) + (k << 8) + n]);
}
// prep: plain fp32 -> bf16 convert (W_ih/W_hh are already [N=768][K=256] = B^T)
__global__ __launch_bounds__(256)
void k_prep_cvt(const float* __restrict__ src, u16* __restrict__ dst, int n) {
    int i = blockIdx.x * 256 + threadIdx.x;
    if (i < n) dst[i] = f2bf(src[i]);
}

// ---------------------------------------------------------------------------
// h0 = emb[x] -> bf16
// ---------------------------------------------------------------------------
__global__ __launch_bounds__(256)
void k_embed(const int* __restrict__ x, const float* __restrict__ emb,
             u16* __restrict__ h) {
    int idx = blockIdx.x * 256 + threadIdx.x;       // 8-elem chunk id
    int row = idx >> 5, c8 = idx & 31;
    long long tok = x[row];
    const float4* e = reinterpret_cast<const float4*>(emb + tok * Hh + c8 * 8);
    float4 a = e[0], b = e[1];
    bf16x8 v;
    v[0]=(short)f2bf(a.x); v[1]=(short)f2bf(a.y); v[2]=(short)f2bf(a.z); v[3]=(short)f2bf(a.w);
    v[4]=(short)f2bf(b.x); v[5]=(short)f2bf(b.y); v[6]=(short)f2bf(b.z); v[7]=(short)f2bf(b.w);
    ((bf16x8*)h)[idx] = v;
}

// ---------------------------------------------------------------------------
// m[b,s,:] = h[b,s-1]@W0 + h[b,s+1]@W1 + h[b,s]@W2 (+ boundary-aware bias)
// MFMA GEMM: M=32768, N=256, K=768 (3 shifted segments). BM=BN=128, BK=32.
// 4 waves (2x2), each 64x64 = 4x4 frags of 16x16x32.
// ---------------------------------------------------------------------------
__global__ __launch_bounds__(256)
void k_edges(const u16* __restrict__ h, const u16* __restrict__ WeT,
             const float* __restrict__ b_edge, u16* __restrict__ m) {
    __shared__ u16 As[128 * 32];
    __shared__ u16 Bs[128 * 32];
    const int t = threadIdx.x;
    const int lane = t & 63, wid = t >> 6;
    const int rowBlk = blockIdx.y * 128, colBlk = blockIdx.x * 128;
    const int wr = (wid >> 1) * 64, wc = (wid & 1) * 64;
    const int lr = lane & 15, kch = lane >> 4;

    f32x4 acc[4][4];
    #pragma unroll
    for (int a = 0; a < 4; ++a)
        #pragma unroll
        for (int b = 0; b < 4; ++b) acc[a][b] = 0.0f;

    for (int ks = 0; ks < 24; ++ks) {
        const int k0 = ks * 32;
        const int seg = k0 >> 8;                 // 0:fwd(s-1) 1:bwd(s+1) 2:self
        const int kk0 = k0 & 255;
        const int dd = (seg == 0) ? -1 : (seg == 1) ? 1 : 0;
        #pragma unroll
        for (int i = 0; i < 2; ++i) {
            int c = t + i * 256;                 // 512 chunks each for A and B
            int r = c >> 2, kc = c & 3;
            // A: shifted h rows, zero at sequence boundary
            int grow = rowBlk + r;
            int s = grow & (Ss - 1);
            int srcs = s + dd;
            bf16x8 v = 0;
            if (srcs >= 0 && srcs < Ss)
                v = *(const bf16x8*)(h + ((grow & ~(Ss - 1)) + srcs) * Hh + kk0 + kc * 8);
            ((bf16x8*)As)[swz(r, kc)] = v;
            // B^T: WeT[seg][n][k]
            bf16x8 w = *(const bf16x8*)(WeT + (seg << 16) + (colBlk + r) * Hh + kk0 + kc * 8);
            ((bf16x8*)Bs)[swz(r, kc)] = w;
        }
        __syncthreads();
        bf16x8 af[4], bfr[4];
        #pragma unroll
        for (int f = 0; f < 4; ++f) {
            int ra = wr + f * 16 + lr;
            af[f]  = ((const bf16x8*)As)[swz(ra, kch)];
            int rb = wc + f * 16 + lr;
            bfr[f] = ((const bf16x8*)Bs)[swz(rb, kch)];
        }
        #pragma unroll
        for (int fm = 0; fm < 4; ++fm)
            #pragma unroll
            for (int fn = 0; fn < 4; ++fn)
                acc[fm][fn] = MFMA(af[fm], bfr[fn], acc[fm][fn]);
        __syncthreads();
    }
    // epilogue: C/D layout col=lane&15, row=(lane>>4)*4+i
    #pragma unroll
    for (int fm = 0; fm < 4; ++fm)
        #pragma unroll
        for (int i = 0; i < 4; ++i) {
            int row = rowBlk + wr + fm * 16 + kch * 4 + i;
            int s = row & (Ss - 1);
            #pragma unroll
            for (int fn = 0; fn < 4; ++fn) {
                int col = colBlk + wc + fn * 16 + lr;
                float bias = b_edge[2 * Hh + col]
                           + (s > 0      ? b_edge[col]      : 0.f)
                           + (s < Ss - 1 ? b_edge[Hh + col] : 0.f);
                m[row * Hh + col] = f2bf(acc[fm][fn][i] + bias);
            }
        }
}

// ---------------------------------------------------------------------------
// Fused GRU step: gi = m@W_ih.T, gh = h@W_hh.T (MFMA, 6 accumulator sets),
// pointwise GRU epilogue -> hout (bf16).
// Block: 128 rows x 32 h-cols. 4 waves stacked in rows (32 rows each).
// ---------------------------------------------------------------------------
__global__ __launch_bounds__(256)
void k_gru(const u16* __restrict__ m, const u16* __restrict__ hin,
           u16* __restrict__ hout,
           const u16* __restrict__ Wihb, const u16* __restrict__ Whhb,
           const float* __restrict__ b_ih, const float* __restrict__ b_hh) {
    __shared__ u16 Am[128 * 32];
    __shared__ u16 Ah[128 * 32];
    __shared__ u16 Bs[6 * 32 * 32];
    const int t = threadIdx.x;
    const int lane = t & 63, wid = t >> 6;
    const int rowBlk = blockIdx.y * 128;
    const int hc0 = blockIdx.x * 32;
    const int wrow = wid * 32;
    const int lr = lane & 15, kch = lane >> 4;

    f32x4 acc[6][2][2];
    #pragma unroll
    for (int g = 0; g < 6; ++g)
        #pragma unroll
        for (int a = 0; a < 2; ++a)
            #pragma unroll
            for (int b = 0; b < 2; ++b) acc[g][a][b] = 0.0f;

    for (int ks = 0; ks < 8; ++ks) {
        const int k0 = ks * 32;
        #pragma unroll
        for (int i = 0; i < 2; ++i) {            // Am + Ah: 512 chunks each
            int c = t + i * 256;
            int r = c >> 2, kc = c & 3;
            ((bf16x8*)Am)[swz(r, kc)] = *(const bf16x8*)(m   + (rowBlk + r) * Hh + k0 + kc * 8);
            ((bf16x8*)Ah)[swz(r, kc)] = *(const bf16x8*)(hin + (rowBlk + r) * Hh + k0 + kc * 8);
        }
        #pragma unroll
        for (int i = 0; i < 3; ++i) {            // B: 6 strips x 128 chunks
            int cb = t + i * 256;
            int g = cb >> 7, r = (cb & 127) >> 2, kc = cb & 3;
            const u16* W = (g < 3) ? Wihb : Whhb;
            int n = ((g < 3) ? g : g - 3) * Hh + hc0 + r;
            ((bf16x8*)(Bs + (g << 10)))[swz(r, kc)] = *(const bf16x8*)(W + n * Hh + k0 + kc * 8);
        }
        __syncthreads();
        bf16x8 am[2], ah[2];
        #pragma unroll
        for (int f = 0; f < 2; ++f) {
            int ra = wrow + f * 16 + lr;
            am[f] = ((const bf16x8*)Am)[swz(ra, kch)];
            ah[f] = ((const bf16x8*)Ah)[swz(ra, kch)];
        }
        #pragma unroll
        for (int g = 0; g < 6; ++g) {
            const bf16x8* bp = (const bf16x8*)(Bs + (g << 10));
            bf16x8 b0 = bp[swz(lr, kch)];
            bf16x8 b1 = bp[swz(16 + lr, kch)];
            #pragma unroll
            for (int fm = 0; fm < 2; ++fm) {
                bf16x8 a = (g < 3) ? am[fm] : ah[fm];
                acc[g][fm][0] = MFMA(a, b0, acc[g][fm][0]);
                acc[g][fm][1] = MFMA(a, b1, acc[g][fm][1]);
            }
        }
        __syncthreads();
    }
    // GRU pointwise epilogue
    #pragma unroll
    for (int fm = 0; fm < 2; ++fm)
        #pragma unroll
        for (int fn = 0; fn < 2; ++fn)
            #pragma unroll
            for (int i = 0; i < 4; ++i) {
                int row = rowBlk + wrow + fm * 16 + kch * 4 + i;
                int col = hc0 + fn * 16 + lr;
                float ir  = acc[0][fm][fn][i] + b_ih[col];
                float iz  = acc[1][fm][fn][i] + b_ih[Hh + col];
                float in_ = acc[2][fm][fn][i] + b_ih[2 * Hh + col];
                float hr  = acc[3][fm][fn][i] + b_hh[col];
                float hz  = acc[4][fm][fn][i] + b_hh[Hh + col];
                float hn  = acc[5][fm][fn][i] + b_hh[2 * Hh + col];
                float r  = 1.f / (1.f + __expf(-(ir + hr)));
                float z  = 1.f / (1.f + __expf(-(iz + hz)));
                float ng = tanhf(in_ + r * hn);
                float hold = bf2f(hin[row * Hh + col]);
                hout[row * Hh + col] = f2bf((1.f - z) * ng + z * hold);
            }
}

// ---------------------------------------------------------------------------
// out = last @ out_w.T + out_b ; last = h[:, S-1, :] (bf16 -> fp32 in LDS)
// ---------------------------------------------------------------------------
__global__ __launch_bounds__(256)
void k_out(const u16* __restrict__ h, const float* __restrict__ out_w,
           const float* __restrict__ out_b, float* __restrict__ out) {
    __shared__ float L[Bb][Hh + 1];
    const int t = threadIdx.x;
    #pragma unroll
    for (int i = 0; i < 8; ++i) {
        int lin = t + i * 256;                  // 2048 chunks of 8
        int r = lin >> 5, c8 = lin & 31;
        bf16x8 v = ((const bf16x8*)(h + ((size_t)r * Ss + (Ss - 1)) * Hh))[c8];
        #pragma unroll
        for (int j = 0; j < 8; ++j) L[r][c8 * 8 + j] = bf2f((u16)v[j]);
    }
    __syncthreads();
    const int n = blockIdx.x * 256 + t;         // V = 125 * 256
    float acc[Bb];
    #pragma unroll
    for (int r = 0; r < Bb; ++r) acc[r] = 0.f;
    const float4* wr = reinterpret_cast<const float4*>(out_w) + n * 64;
    for (int k4 = 0; k4 < 64; ++k4) {
        float4 w = wr[k4];
        #pragma unroll
        for (int r = 0; r < Bb; ++r)
            acc[r] += L[r][k4*4+0]*w.x + L[r][k4*4+1]*w.y
                    + L[r][k4*4+2]*w.z + L[r][k4*4+3]*w.w;
    }
    float bb = out_b[n];
    #pragma unroll
    for (int r = 0; r < Bb; ++r) out[r * Vv + n] = acc[r] + bb;
}

// ---------------------------------------------------------------------------
extern "C" void kernel_launch(void* const* d_in, const int* in_sizes, int n_in,
                              void* d_out, int out_size, void* d_ws, size_t ws_size,
                              hipStream_t stream) {
    const int*   x      = (const int*)  d_in[0];
    const float* emb    = (const float*)d_in[1];
    const float* W_edge = (const float*)d_in[2];
    const float* b_edge = (const float*)d_in[3];
    const float* W_ih   = (const float*)d_in[4];
    const float* W_hh   = (const float*)d_in[5];
    const float* b_ih   = (const float*)d_in[6];
    const float* b_hh   = (const float*)d_in[7];
    const float* out_w  = (const float*)d_in[8];
    const float* out_b  = (const float*)d_in[9];
    float* out = (float*)d_out;

    // ws (bf16): hA | hB | m | WeT | Wih | Whh  = ~51.5 MB
    u16* hA  = (u16*)d_ws;
    u16* hB  = hA + (size_t)BS * Hh;
    u16* mm  = hB + (size_t)BS * Hh;
    u16* WeT = mm + (size_t)BS * Hh;
    u16* Wih = WeT + 3 * Hh * Hh;
    u16* Whh = Wih + 3 * Hh * Hh;

    k_prep_wet<<<768, 256, 0, stream>>>(W_edge, WeT);
    k_prep_cvt<<<768, 256, 0, stream>>>(W_ih, Wih, 3 * Hh * Hh);
    k_prep_cvt<<<768, 256, 0, stream>>>(W_hh, Whh, 3 * Hh * Hh);
    k_embed<<<BS * Hh / 8 / 256, 256, 0, stream>>>(x, emb, hA);

    u16* cur = hA;
    u16* nxt = hB;
    for (int step = 0; step < NSTEPS; ++step) {
        k_edges<<<dim3(2, BS / 128), 256, 0, stream>>>(cur, WeT, b_edge, mm);
        k_gru  <<<dim3(8, BS / 128), 256, 0, stream>>>(mm, cur, nxt, Wih, Whh, b_ih, b_hh);
        u16* tmp = cur; cur = nxt; nxt = tmp;
    }
    k_out<<<Vv / 256, 256, 0, stream>>>(cur, out_w, out_b, out);
}